// Round 2
// baseline (594.364 us; speedup 1.0000x reference)
//
#include <hip/hip_runtime.h>
#include <hip/hip_bf16.h>

#define D_MODEL 1024
#define N_HEADS 16
#define HEAD_DIM 64
#define BATCH 2
#define SEQ 2048
#define NMEM 8

typedef __attribute__((ext_vector_type(8))) short vshort8;
typedef __attribute__((ext_vector_type(4))) short vshort4;
typedef __attribute__((ext_vector_type(4))) float f32x4;

static __device__ __forceinline__ short f2bf(float f) {
    unsigned u = __builtin_bit_cast(unsigned, f);
    unsigned r = u + 0x7fffu + ((u >> 16) & 1u);
    return (short)(r >> 16);
}
static __device__ __forceinline__ float bf2f(short s) {
    unsigned u = ((unsigned)(unsigned short)s) << 16;
    return __builtin_bit_cast(float, u);
}

static __device__ __forceinline__ f32x4 mfma16x16x32(vshort8 a, vshort8 b, f32x4 c) {
    return __builtin_amdgcn_mfma_f32_16x16x32_bf16(a, b, c, 0, 0, 0);
}

// ---------------- cast fp32 -> bf16 (vectorized) ----------------
__global__ void cast_f32_bf16(const float* __restrict__ in, short* __restrict__ out, int n4) {
    int i = blockIdx.x * blockDim.x + threadIdx.x;
    if (i >= n4) return;
    float4 v = reinterpret_cast<const float4*>(in)[i];
    vshort4 o;
    o.x = f2bf(v.x); o.y = f2bf(v.y); o.z = f2bf(v.z); o.w = f2bf(v.w);
    reinterpret_cast<vshort4*>(out)[i] = o;
}

// ---------------- transpose + cast: in[R][C] fp32 -> out[C][R] bf16 ----------------
__global__ void transpose_cast(const float* __restrict__ in, short* __restrict__ out, int R, int C) {
    __shared__ float tile[32][33];
    int n0 = blockIdx.x * 32;   // C index base
    int k0 = blockIdx.y * 32;   // R index base
    int tx = threadIdx.x, ty = threadIdx.y;
    #pragma unroll
    for (int i = 0; i < 4; i++) {
        int r = ty + i * 8;
        tile[r][tx] = in[(k0 + r) * C + n0 + tx];
    }
    __syncthreads();
    #pragma unroll
    for (int i = 0; i < 4; i++) {
        int r = ty + i * 8;
        out[(n0 + r) * R + k0 + tx] = f2bf(tile[tx][r]);
    }
}

// ---------------- generic bf16 GEMM: C[M][N] = A[M][K] * Bt[N][K]^T + bias ----------------
// EPI 0: write fp32 C to Cout (ldc=N). EPI 1: qkv split epilogue.
#define BM 128
#define BN 128
#define BK 32

template<int EPI>
__global__ __launch_bounds__(256) void gemm_bf16(
    const short* __restrict__ A, const short* __restrict__ Bt,
    int M, int N, int K,
    const float* __restrict__ bias,
    float* __restrict__ Cout,
    short* __restrict__ Qb, short* __restrict__ Kb, short* __restrict__ Vt,
    float* __restrict__ k_out, float* __restrict__ v_out)
{
    __shared__ short As[BM][40];
    __shared__ short Bs[BN][40];
    int m0 = blockIdx.x * BM, n0 = blockIdx.y * BN;
    int tid = threadIdx.x;
    int wave = tid >> 6, lane = tid & 63;
    int wr = wave >> 1, wc = wave & 1;
    int lo = lane & 15, hi = lane >> 4;

    f32x4 acc[4][4];
    #pragma unroll
    for (int i = 0; i < 4; i++)
        #pragma unroll
        for (int j = 0; j < 4; j++)
            acc[i][j] = (f32x4){0.f, 0.f, 0.f, 0.f};

    for (int k0 = 0; k0 < K; k0 += BK) {
        __syncthreads();
        #pragma unroll
        for (int p = 0; p < 2; p++) {
            int i = p * 256 + tid;
            int row = i >> 2, ch = i & 3;
            *reinterpret_cast<vshort8*>(&As[row][ch * 8]) =
                *reinterpret_cast<const vshort8*>(&A[(m0 + row) * K + k0 + ch * 8]);
            *reinterpret_cast<vshort8*>(&Bs[row][ch * 8]) =
                *reinterpret_cast<const vshort8*>(&Bt[(n0 + row) * K + k0 + ch * 8]);
        }
        __syncthreads();
        vshort8 av[4], bv[4];
        #pragma unroll
        for (int fr = 0; fr < 4; fr++)
            av[fr] = *reinterpret_cast<const vshort8*>(&As[wr * 64 + fr * 16 + lo][hi * 8]);
        #pragma unroll
        for (int fc = 0; fc < 4; fc++)
            bv[fc] = *reinterpret_cast<const vshort8*>(&Bs[wc * 64 + fc * 16 + lo][hi * 8]);
        #pragma unroll
        for (int fr = 0; fr < 4; fr++)
            #pragma unroll
            for (int fc = 0; fc < 4; fc++)
                acc[fr][fc] = mfma16x16x32(av[fr], bv[fc], acc[fr][fc]);
    }

    #pragma unroll
    for (int fr = 0; fr < 4; fr++) {
        #pragma unroll
        for (int fc = 0; fc < 4; fc++) {
            int col = n0 + wc * 64 + fc * 16 + lo;
            float bb = bias[col];
            #pragma unroll
            for (int j = 0; j < 4; j++) {
                int row = m0 + wr * 64 + fr * 16 + hi * 4 + j;
                float val = acc[fr][fc][j] + bb;
                if (EPI == 0) {
                    Cout[row * N + col] = val;
                } else {
                    int sec = col >> 10, c = col & 1023;
                    int h = c >> 6, d = c & 63;
                    int b = row >> 11, s = row & 2047;
                    int idx = ((b * 16 + h) * 2048 + s) * 64 + d;
                    if (sec == 0) {
                        Qb[idx] = f2bf(val);
                    } else if (sec == 1) {
                        k_out[idx] = val;
                        Kb[idx] = f2bf(val);
                    } else {
                        v_out[idx] = val;
                        Vt[((b * 16 + h) * 64 + d) * 2048 + s] = f2bf(val);
                    }
                }
            }
        }
    }
}

// ---------------- flash attention with per-row memory slots ----------------
// grid: (qblocks=32, bh=32). 256 threads = 4 waves; each wave owns 16 q rows.
__global__ __launch_bounds__(256) void attn_kernel(
    const short* __restrict__ Qb, const short* __restrict__ Kb, const short* __restrict__ Vt,
    const float* __restrict__ pk, const float* __restrict__ pv,
    short* __restrict__ ctx)
{
    __shared__ short P[4][16][72];
    int qblk = blockIdx.x, bh = blockIdx.y;
    int b = bh >> 4, h = bh & 15;
    int wave = threadIdx.x >> 6, lane = threadIdx.x & 63;
    int lo = lane & 15, hi = lane >> 4;
    int qbase = qblk * 64 + wave * 16;

    const short* Qh = Qb + bh * SEQ * 64;
    const short* Kh = Kb + bh * SEQ * 64;
    const short* Vh = Vt + bh * 64 * SEQ;

    // Q fragments (A-operand): row = lo, k = ks*32 + hi*8 + j
    vshort8 aq[2];
    #pragma unroll
    for (int ks = 0; ks < 2; ks++)
        aq[ks] = *reinterpret_cast<const vshort8*>(&Qh[(qbase + lo) * 64 + ks * 32 + hi * 8]);

    float m_r[4], ell[4];
    f32x4 o[4];

    // ---- init online-softmax state from the 8 per-row memory slots ----
    float qv[4][4];
    #pragma unroll
    for (int j = 0; j < 4; j++)
        #pragma unroll
        for (int t = 0; t < 4; t++)
            qv[j][t] = bf2f(Qh[(qbase + hi * 4 + j) * 64 + t * 16 + lo]);

    float w[4][8];
    #pragma unroll
    for (int j = 0; j < 4; j++) {
        int sg = bh * SEQ + qbase + hi * 4 + j;
        #pragma unroll
        for (int ml = 0; ml < 8; ml++) {
            const float* pkp = pk + (sg * 8 + ml) * 64;
            float partial = 0.f;
            #pragma unroll
            for (int t = 0; t < 4; t++)
                partial += qv[j][t] * pkp[t * 16 + lo];
            partial += __shfl_xor(partial, 1);
            partial += __shfl_xor(partial, 2);
            partial += __shfl_xor(partial, 4);
            partial += __shfl_xor(partial, 8);
            w[j][ml] = partial * 0.125f;
        }
        float mm = w[j][0];
        #pragma unroll
        for (int ml = 1; ml < 8; ml++) mm = fmaxf(mm, w[j][ml]);
        m_r[j] = mm;
        float e = 0.f;
        #pragma unroll
        for (int ml = 0; ml < 8; ml++) { w[j][ml] = __expf(w[j][ml] - mm); e += w[j][ml]; }
        ell[j] = e;
    }
    #pragma unroll
    for (int g = 0; g < 4; g++) {
        f32x4 og = (f32x4){0.f, 0.f, 0.f, 0.f};
        #pragma unroll
        for (int j = 0; j < 4; j++) {
            int sg = bh * SEQ + qbase + hi * 4 + j;
            float sum = 0.f;
            #pragma unroll
            for (int ml = 0; ml < 8; ml++)
                sum += w[j][ml] * pv[(sg * 8 + ml) * 64 + g * 16 + lo];
            og[j] = sum;
        }
        o[g] = og;
    }

    // ---- causal kv tiles of 64 ----
    for (int kvt = 0; kvt <= qblk; kvt++) {
        int kvbase = kvt * 64;
        f32x4 sc[4];
        #pragma unroll
        for (int g = 0; g < 4; g++) {
            vshort8 bk0 = *reinterpret_cast<const vshort8*>(&Kh[(kvbase + g * 16 + lo) * 64 + hi * 8]);
            vshort8 bk1 = *reinterpret_cast<const vshort8*>(&Kh[(kvbase + g * 16 + lo) * 64 + 32 + hi * 8]);
            f32x4 z = (f32x4){0.f, 0.f, 0.f, 0.f};
            z = mfma16x16x32(aq[0], bk0, z);
            sc[g] = mfma16x16x32(aq[1], bk1, z);
        }
        bool diag = (kvt == qblk);
        float p[4][4];
        float tm[4];
        #pragma unroll
        for (int j = 0; j < 4; j++) tm[j] = -3.0e38f;
        #pragma unroll
        for (int g = 0; g < 4; g++)
            #pragma unroll
            for (int j = 0; j < 4; j++) {
                float sv = sc[g][j] * 0.125f;
                if (diag && (kvbase + g * 16 + lo > qbase + hi * 4 + j)) sv = -3.0e38f;
                p[g][j] = sv;
                tm[j] = fmaxf(tm[j], sv);
            }
        #pragma unroll
        for (int j = 0; j < 4; j++) {
            tm[j] = fmaxf(tm[j], __shfl_xor(tm[j], 1));
            tm[j] = fmaxf(tm[j], __shfl_xor(tm[j], 2));
            tm[j] = fmaxf(tm[j], __shfl_xor(tm[j], 4));
            tm[j] = fmaxf(tm[j], __shfl_xor(tm[j], 8));
        }
        float fac[4], rs[4];
        #pragma unroll
        for (int j = 0; j < 4; j++) {
            float mn = fmaxf(m_r[j], tm[j]);
            fac[j] = __expf(m_r[j] - mn);
            m_r[j] = mn;
            rs[j] = 0.f;
        }
        #pragma unroll
        for (int g = 0; g < 4; g++)
            #pragma unroll
            for (int j = 0; j < 4; j++) {
                p[g][j] = __expf(p[g][j] - m_r[j]);
                rs[j] += p[g][j];
            }
        #pragma unroll
        for (int j = 0; j < 4; j++) {
            rs[j] += __shfl_xor(rs[j], 1);
            rs[j] += __shfl_xor(rs[j], 2);
            rs[j] += __shfl_xor(rs[j], 4);
            rs[j] += __shfl_xor(rs[j], 8);
            ell[j] = ell[j] * fac[j] + rs[j];
        }
        #pragma unroll
        for (int g = 0; g < 4; g++)
            #pragma unroll
            for (int j = 0; j < 4; j++)
                o[g][j] *= fac[j];

        // P -> LDS (per-wave region), re-fragment as A-operand
        #pragma unroll
        for (int g = 0; g < 4; g++)
            #pragma unroll
            for (int j = 0; j < 4; j++)
                P[wave][hi * 4 + j][g * 16 + lo] = f2bf(p[g][j]);

        vshort8 ap0 = *reinterpret_cast<const vshort8*>(&P[wave][lo][hi * 8]);
        vshort8 ap1 = *reinterpret_cast<const vshort8*>(&P[wave][lo][32 + hi * 8]);
        #pragma unroll
        for (int g = 0; g < 4; g++) {
            vshort8 bv0 = *reinterpret_cast<const vshort8*>(&Vh[(g * 16 + lo) * SEQ + kvbase + hi * 8]);
            vshort8 bv1 = *reinterpret_cast<const vshort8*>(&Vh[(g * 16 + lo) * SEQ + kvbase + 32 + hi * 8]);
            o[g] = mfma16x16x32(ap0, bv0, o[g]);
            o[g] = mfma16x16x32(ap1, bv1, o[g]);
        }
    }

    // ---- normalize + write ctx (bf16, row layout [b*S+s][h*64+d]) ----
    #pragma unroll
    for (int g = 0; g < 4; g++)
        #pragma unroll
        for (int j = 0; j < 4; j++) {
            int s = qbase + hi * 4 + j;
            float val = o[g][j] / ell[j];
            ctx[(b * SEQ + s) * D_MODEL + h * 64 + g * 16 + lo] = f2bf(val);
        }
}

extern "C" void kernel_launch(void* const* d_in, const int* in_sizes, int n_in,
                              void* d_out, int out_size, void* d_ws, size_t ws_size,
                              hipStream_t stream) {
    const float* x    = (const float*)d_in[0];
    const float* pk   = (const float*)d_in[1];
    const float* pv   = (const float*)d_in[2];
    const float* Wqkv = (const float*)d_in[3];
    const float* bqkv = (const float*)d_in[4];
    const float* Wout = (const float*)d_in[5];
    const float* bout = (const float*)d_in[6];

    float* out   = (float*)d_out;
    float* k_out = out + 4194304;
    float* v_out = out + 8388608;

    char* ws = (char*)d_ws;
    short* Xb    = (short*)(ws);                         // 8 MB (reused as ctx later)
    short* Wqkvt = (short*)(ws + (size_t)(8  << 20));    // 6 MB
    short* Woutt = (short*)(ws + (size_t)(14 << 20));    // 2 MB
    short* Qb    = (short*)(ws + (size_t)(16 << 20));    // 8 MB
    short* Kb    = (short*)(ws + (size_t)(24 << 20));    // 8 MB
    short* Vt    = (short*)(ws + (size_t)(32 << 20));    // 8 MB
    short* ctx   = Xb;

    cast_f32_bf16<<<4096, 256, 0, stream>>>(x, Xb, 4194304 / 4);
    dim3 tb(32, 8);
    transpose_cast<<<dim3(96, 32), tb, 0, stream>>>(Wqkv, Wqkvt, 1024, 3072);
    transpose_cast<<<dim3(32, 32), tb, 0, stream>>>(Wout, Woutt, 1024, 1024);

    gemm_bf16<1><<<dim3(32, 24), 256, 0, stream>>>(
        Xb, Wqkvt, 4096, 3072, 1024, bqkv,
        nullptr, Qb, Kb, Vt, k_out, v_out);

    attn_kernel<<<dim3(32, 32), 256, 0, stream>>>(Qb, Kb, Vt, pk, pv, ctx);

    gemm_bf16<0><<<dim3(32, 8), 256, 0, stream>>>(
        ctx, Woutt, 4096, 1024, 1024, bout,
        out, nullptr, nullptr, nullptr, nullptr, nullptr);
}

// Round 4
// 455.768 us; speedup vs baseline: 1.3041x; 1.3041x over previous
//
#include <hip/hip_runtime.h>
#include <hip/hip_bf16.h>

#define D_MODEL 1024
#define N_HEADS 16
#define HEAD_DIM 64
#define BATCH 2
#define SEQ 2048
#define NMEM 8

typedef __attribute__((ext_vector_type(8))) short vshort8;
typedef __attribute__((ext_vector_type(4))) short vshort4;
typedef __attribute__((ext_vector_type(4))) float f32x4;

static __device__ __forceinline__ short f2bf(float f) {
    unsigned u = __builtin_bit_cast(unsigned, f);
    unsigned r = u + 0x7fffu + ((u >> 16) & 1u);
    return (short)(r >> 16);
}
static __device__ __forceinline__ float bf2f(short s) {
    unsigned u = ((unsigned)(unsigned short)s) << 16;
    return __builtin_bit_cast(float, u);
}

static __device__ __forceinline__ f32x4 mfma16x16x32(vshort8 a, vshort8 b, f32x4 c) {
    return __builtin_amdgcn_mfma_f32_16x16x32_bf16(a, b, c, 0, 0, 0);
}

typedef const __attribute__((address_space(1))) char* gptr_t;
typedef __attribute__((address_space(3))) char* lptr_t;
static __device__ __forceinline__ void gload_lds16(const void* g, void* l) {
    __builtin_amdgcn_global_load_lds((gptr_t)g, (lptr_t)l, 16, 0, 0);
}

// ---------------- cast fp32 -> bf16 (vectorized) ----------------
__global__ void cast_f32_bf16(const float* __restrict__ in, short* __restrict__ out, int n4) {
    int i = blockIdx.x * blockDim.x + threadIdx.x;
    if (i >= n4) return;
    float4 v = reinterpret_cast<const float4*>(in)[i];
    vshort4 o;
    o.x = f2bf(v.x); o.y = f2bf(v.y); o.z = f2bf(v.z); o.w = f2bf(v.w);
    reinterpret_cast<vshort4*>(out)[i] = o;
}

// ---------------- transpose + cast: in[R][C] fp32 -> out[C][R] bf16 ----------------
__global__ void transpose_cast(const float* __restrict__ in, short* __restrict__ out, int R, int C) {
    __shared__ float tile[32][33];
    int n0 = blockIdx.x * 32;
    int k0 = blockIdx.y * 32;
    int tx = threadIdx.x, ty = threadIdx.y;
    #pragma unroll
    for (int i = 0; i < 4; i++) {
        int r = ty + i * 8;
        tile[r][tx] = in[(k0 + r) * C + n0 + tx];
    }
    __syncthreads();
    #pragma unroll
    for (int i = 0; i < 4; i++) {
        int r = ty + i * 8;
        out[(n0 + r) * R + k0 + tx] = f2bf(tile[tx][r]);
    }
}

// ---------------- bf16 GEMM (m97-style global_load_lds staging) ----------------
#define BM 128
#define BN 128
#define BK 32

template<int EPI>
__global__ __launch_bounds__(256) void gemm_bf16(
    const short* __restrict__ A, const short* __restrict__ Bt,
    int M, int N, int K,
    const float* __restrict__ bias,
    float* __restrict__ Cout,
    short* __restrict__ Qb, short* __restrict__ Kb, short* __restrict__ Vt,
    float* __restrict__ k_out, float* __restrict__ v_out)
{
    __shared__ short As[BM][BK];
    __shared__ short Bs[BN][BK];
    int m0 = blockIdx.x * BM, n0 = blockIdx.y * BN;
    int tid = threadIdx.x;
    int wave = tid >> 6, lane = tid & 63;
    int wr = wave >> 1, wc = wave & 1;
    int lo = lane & 15, hi = lane >> 4;

    f32x4 acc[4][4];
    #pragma unroll
    for (int i = 0; i < 4; i++)
        #pragma unroll
        for (int j = 0; j < 4; j++)
            acc[i][j] = (f32x4){0.f, 0.f, 0.f, 0.f};

    int srow = wave * 16 + (lane >> 2);   // row within 64-row round
    int sce  = (lane & 3) * 8;            // element col offset

    for (int k0 = 0; k0 < K; k0 += BK) {
        __syncthreads();   // prev compute done before overwrite
        #pragma unroll
        for (int r = 0; r < 2; r++) {
            int row = r * 64 + srow;
            gload_lds16(&A[(size_t)(m0 + row) * K + k0 + sce],
                        ((char*)&As[0][0]) + (size_t)(r * 64 + wave * 16) * 64);
            gload_lds16(&Bt[(size_t)(n0 + row) * K + k0 + sce],
                        ((char*)&Bs[0][0]) + (size_t)(r * 64 + wave * 16) * 64);
        }
        __syncthreads();   // drains vmcnt (stage complete)
        vshort8 av[4], bv[4];
        #pragma unroll
        for (int fr = 0; fr < 4; fr++)
            av[fr] = *reinterpret_cast<const vshort8*>(&As[wr * 64 + fr * 16 + lo][hi * 8]);
        #pragma unroll
        for (int fc = 0; fc < 4; fc++)
            bv[fc] = *reinterpret_cast<const vshort8*>(&Bs[wc * 64 + fc * 16 + lo][hi * 8]);
        #pragma unroll
        for (int fr = 0; fr < 4; fr++)
            #pragma unroll
            for (int fc = 0; fc < 4; fc++)
                acc[fr][fc] = mfma16x16x32(av[fr], bv[fc], acc[fr][fc]);
    }

    #pragma unroll
    for (int fr = 0; fr < 4; fr++) {
        #pragma unroll
        for (int fc = 0; fc < 4; fc++) {
            int col = n0 + wc * 64 + fc * 16 + lo;
            float bb = bias[col];
            #pragma unroll
            for (int j = 0; j < 4; j++) {
                int row = m0 + wr * 64 + fr * 16 + hi * 4 + j;
                float val = acc[fr][fc][j] + bb;
                if (EPI == 0) {
                    Cout[row * N + col] = val;
                } else {
                    int sec = col >> 10, c = col & 1023;
                    int h = c >> 6, d = c & 63;
                    int b = row >> 11, s = row & 2047;
                    int idx = ((b * 16 + h) * 2048 + s) * 64 + d;
                    if (sec == 0) {
                        Qb[idx] = f2bf(val);
                    } else if (sec == 1) {
                        k_out[idx] = val;
                        Kb[idx] = f2bf(val);
                    } else {
                        v_out[idx] = val;
                        Vt[((b * 16 + h) * 64 + d) * 2048 + s] = f2bf(val);
                    }
                }
            }
        }
    }
}

// ---------------- flash attention, 2-phase pipelined, paired q-tiles ----------------
// grid: (bh=32, pair=16). 256 threads = 4 waves; each wave owns 16 q rows of a
// 64-row q tile. Each block processes q-tiles {31-pair, pair} (uniform work).
__global__ __launch_bounds__(256) void attn_kernel(
    const short* __restrict__ Qb, const short* __restrict__ Kb, const short* __restrict__ Vt,
    const float* __restrict__ pk, const float* __restrict__ pv,
    short* __restrict__ ctx)
{
    __shared__ short Ks[2][64][64];   // [buf][kv][d]   XOR-swizzled rows
    __shared__ short Vs[2][64][64];   // [buf][d][kv]   XOR-swizzled rows
    __shared__ short P[4][16][72];
    __shared__ float wlds[4][16][8];

    int bh = blockIdx.x, pairidx = blockIdx.y;
    int b = bh >> 4, h = bh & 15;
    int wave = threadIdx.x >> 6, lane = threadIdx.x & 63;
    int lo = lane & 15, hi = lane >> 4;

    const short* Qh = Qb + (size_t)bh * SEQ * 64;
    const short* Kh = Kb + (size_t)bh * SEQ * 64;
    const short* Vh = Vt + (size_t)bh * 64 * SEQ;

    // staging geometry: wave w, lane l covers tile row (rd*32 + w*8 + (l>>3)),
    // dest col (l&7)*16 bytes; source col XOR'd so a swizzled read is linear.
    int st_sub  = lane >> 3;                       // 0..7 row within wave's 8
    int st_csrc = (((lane & 7) ^ st_sub) << 4);    // pre-swizzled source col (bytes)

    for (int pass = 0; pass < 2; pass++) {
        int qblk = (pass == 0) ? (31 - pairidx) : pairidx;
        int qbase = qblk * 64 + wave * 16;

        // ---- prologue: stage kv tile 0 into buf 0 (overlaps mem-slot init) ----
        {
            #pragma unroll
            for (int rd = 0; rd < 2; rd++) {
                int tr = rd * 32 + wave * 8 + st_sub;
                gload_lds16((const char*)Kh + (((size_t)tr) << 7) + st_csrc,
                            ((char*)&Ks[0][0][0]) + rd * 4096 + wave * 1024);
                gload_lds16((const char*)Vh + (((size_t)tr) << 12) + st_csrc,
                            ((char*)&Vs[0][0][0]) + rd * 4096 + wave * 1024);
            }
        }

        // ---- Q fragments ----
        vshort8 aq[2];
        #pragma unroll
        for (int ks = 0; ks < 2; ks++)
            aq[ks] = *reinterpret_cast<const vshort8*>(&Qh[(size_t)(qbase + lo) * 64 + ks * 32 + hi * 8]);

        // ---- mem-slot init, phase A: lane = (row, slot) owns one 64-d dot ----
        {
            int rm = lane >> 2, ml0 = lane & 3;
            size_t srow = (size_t)bh * SEQ + qbase + rm;
            const float4* pkA = reinterpret_cast<const float4*>(pk + (srow * 8 + ml0) * 64);
            const float4* pkB = pkA + 64;   // slot ml0+4 (4*64 floats / 4)
            const short* qrow = Qh + (size_t)(qbase + rm) * 64;
            float dA = 0.f, dB = 0.f;
            #pragma unroll
            for (int t = 0; t < 16; t++) {
                float4 a4 = pkA[t];
                float4 b4 = pkB[t];
                vshort4 q4 = *reinterpret_cast<const vshort4*>(&qrow[t * 4]);
                float q0 = bf2f(q4.x), q1 = bf2f(q4.y), q2 = bf2f(q4.z), q3 = bf2f(q4.w);
                dA += q0 * a4.x + q1 * a4.y + q2 * a4.z + q3 * a4.w;
                dB += q0 * b4.x + q1 * b4.y + q2 * b4.z + q3 * b4.w;
            }
            wlds[wave][rm][ml0]     = dA * 0.125f;
            wlds[wave][rm][ml0 + 4] = dB * 0.125f;
        }
        asm volatile("s_waitcnt lgkmcnt(0)" ::: "memory");  // same-wave LDS visibility

        // ---- mem-slot init, phase B: per-lane softmax state + o init ----
        float m_r[4], ell[4];
        float ew[4][8];
        f32x4 o[4];
        #pragma unroll
        for (int j = 0; j < 4; j++) {
            float mm = -3.0e38f;
            #pragma unroll
            for (int ml = 0; ml < 8; ml++) mm = fmaxf(mm, wlds[wave][hi * 4 + j][ml]);
            m_r[j] = mm;
            float e = 0.f;
            #pragma unroll
            for (int ml = 0; ml < 8; ml++) {
                float t = __expf(wlds[wave][hi * 4 + j][ml] - mm);
                ew[j][ml] = t;
                e += t;
            }
            ell[j] = e;
        }
        #pragma unroll
        for (int g = 0; g < 4; g++) {
            #pragma unroll
            for (int j = 0; j < 4; j++) {
                size_t srow = (size_t)bh * SEQ + qbase + hi * 4 + j;
                const float* pvr = pv + srow * 8 * 64 + g * 16 + lo;
                float acc = 0.f;
                #pragma unroll
                for (int ml = 0; ml < 8; ml++)
                    acc += ew[j][ml] * pvr[ml * 64];
                o[g][j] = acc;
            }
        }

        __syncthreads();   // drains prologue stage (vmcnt 0), all waves ready

        // ---- causal kv loop, 2-phase double-buffer ----
        int buf = 0;
        for (int kvt = 0; kvt <= qblk; kvt++) {
            if (kvt < qblk) {
                int kvbase = (kvt + 1) * 64;
                int nb = buf ^ 1;
                #pragma unroll
                for (int rd = 0; rd < 2; rd++) {
                    int tr = rd * 32 + wave * 8 + st_sub;
                    gload_lds16((const char*)Kh + (((size_t)(kvbase + tr)) << 7) + st_csrc,
                                ((char*)&Ks[nb][0][0]) + rd * 4096 + wave * 1024);
                    gload_lds16((const char*)Vh + (((size_t)tr) << 12) + (size_t)kvbase * 2 + st_csrc,
                                ((char*)&Vs[nb][0][0]) + rd * 4096 + wave * 1024);
                }
            }
            int kvbase = kvt * 64;

            // QK^T from swizzled LDS
            f32x4 sc[4];
            #pragma unroll
            for (int g = 0; g < 4; g++) {
                int kr = g * 16 + lo;
                const char* base = ((const char*)&Ks[buf][0][0]) + kr * 128;
                vshort8 bk0 = *reinterpret_cast<const vshort8*>(base + ((hi * 16) ^ ((kr & 7) << 4)));
                vshort8 bk1 = *reinterpret_cast<const vshort8*>(base + ((64 + hi * 16) ^ ((kr & 7) << 4)));
                f32x4 z = (f32x4){0.f, 0.f, 0.f, 0.f};
                z = mfma16x16x32(aq[0], bk0, z);
                sc[g] = mfma16x16x32(aq[1], bk1, z);
            }
            bool diag = (kvt == qblk);
            float p[4][4];
            float tm[4];
            #pragma unroll
            for (int j = 0; j < 4; j++) tm[j] = -3.0e38f;
            #pragma unroll
            for (int g = 0; g < 4; g++)
                #pragma unroll
                for (int j = 0; j < 4; j++) {
                    float sv = sc[g][j] * 0.125f;
                    if (diag && (kvbase + g * 16 + lo > qbase + hi * 4 + j)) sv = -3.0e38f;
                    p[g][j] = sv;
                    tm[j] = fmaxf(tm[j], sv);
                }
            #pragma unroll
            for (int j = 0; j < 4; j++) {
                tm[j] = fmaxf(tm[j], __shfl_xor(tm[j], 1));
                tm[j] = fmaxf(tm[j], __shfl_xor(tm[j], 2));
                tm[j] = fmaxf(tm[j], __shfl_xor(tm[j], 4));
                tm[j] = fmaxf(tm[j], __shfl_xor(tm[j], 8));
            }
            float fac[4], rs[4];
            #pragma unroll
            for (int j = 0; j < 4; j++) {
                float mn = fmaxf(m_r[j], tm[j]);
                fac[j] = __expf(m_r[j] - mn);
                m_r[j] = mn;
                rs[j] = 0.f;
            }
            #pragma unroll
            for (int g = 0; g < 4; g++)
                #pragma unroll
                for (int j = 0; j < 4; j++) {
                    p[g][j] = __expf(p[g][j] - m_r[j]);
                    rs[j] += p[g][j];
                }
            #pragma unroll
            for (int j = 0; j < 4; j++) {
                rs[j] += __shfl_xor(rs[j], 1);
                rs[j] += __shfl_xor(rs[j], 2);
                rs[j] += __shfl_xor(rs[j], 4);
                rs[j] += __shfl_xor(rs[j], 8);
                ell[j] = ell[j] * fac[j] + rs[j];
            }
            #pragma unroll
            for (int g = 0; g < 4; g++)
                #pragma unroll
                for (int j = 0; j < 4; j++)
                    o[g][j] *= fac[j];

            // P -> per-wave LDS, re-fragment as A-operand
            #pragma unroll
            for (int g = 0; g < 4; g++)
                #pragma unroll
                for (int j = 0; j < 4; j++)
                    P[wave][hi * 4 + j][g * 16 + lo] = f2bf(p[g][j]);

            vshort8 ap0 = *reinterpret_cast<const vshort8*>(&P[wave][lo][hi * 8]);
            vshort8 ap1 = *reinterpret_cast<const vshort8*>(&P[wave][lo][32 + hi * 8]);
            #pragma unroll
            for (int g = 0; g < 4; g++) {
                int vr = g * 16 + lo;
                const char* base = ((const char*)&Vs[buf][0][0]) + vr * 128;
                vshort8 bv0 = *reinterpret_cast<const vshort8*>(base + ((hi * 16) ^ ((vr & 7) << 4)));
                vshort8 bv1 = *reinterpret_cast<const vshort8*>(base + ((64 + hi * 16) ^ ((vr & 7) << 4)));
                o[g] = mfma16x16x32(ap0, bv0, o[g]);
                o[g] = mfma16x16x32(ap1, bv1, o[g]);
            }

            __syncthreads();   // stage drained + all waves done with buf
            buf ^= 1;
        }

        // ---- normalize + write ctx ----
        #pragma unroll
        for (int g = 0; g < 4; g++)
            #pragma unroll
            for (int j = 0; j < 4; j++) {
                int s = qbase + hi * 4 + j;
                float val = o[g][j] / ell[j];
                ctx[(size_t)(b * SEQ + s) * D_MODEL + h * 64 + g * 16 + lo] = f2bf(val);
            }
    }
}

extern "C" void kernel_launch(void* const* d_in, const int* in_sizes, int n_in,
                              void* d_out, int out_size, void* d_ws, size_t ws_size,
                              hipStream_t stream) {
    const float* x    = (const float*)d_in[0];
    const float* pk   = (const float*)d_in[1];
    const float* pv   = (const float*)d_in[2];
    const float* Wqkv = (const float*)d_in[3];
    const float* bqkv = (const float*)d_in[4];
    const float* Wout = (const float*)d_in[5];
    const float* bout = (const float*)d_in[6];

    float* out   = (float*)d_out;
    float* k_out = out + 4194304;
    float* v_out = out + 8388608;

    char* ws = (char*)d_ws;
    short* Xb    = (short*)(ws);                         // 8 MB (reused as ctx later)
    short* Wqkvt = (short*)(ws + (size_t)(8  << 20));    // 6 MB
    short* Woutt = (short*)(ws + (size_t)(14 << 20));    // 2 MB
    short* Qb    = (short*)(ws + (size_t)(16 << 20));    // 8 MB
    short* Kb    = (short*)(ws + (size_t)(24 << 20));    // 8 MB
    short* Vt    = (short*)(ws + (size_t)(32 << 20));    // 8 MB
    short* ctx   = Xb;

    cast_f32_bf16<<<4096, 256, 0, stream>>>(x, Xb, 4194304 / 4);
    dim3 tb(32, 8);
    transpose_cast<<<dim3(96, 32), tb, 0, stream>>>(Wqkv, Wqkvt, 1024, 3072);
    transpose_cast<<<dim3(32, 32), tb, 0, stream>>>(Wout, Woutt, 1024, 1024);

    gemm_bf16<1><<<dim3(32, 24), 256, 0, stream>>>(
        Xb, Wqkvt, 4096, 3072, 1024, bqkv,
        nullptr, Qb, Kb, Vt, k_out, v_out);

    attn_kernel<<<dim3(32, 16), 256, 0, stream>>>(Qb, Kb, Vt, pk, pv, ctx);

    gemm_bf16<0><<<dim3(32, 8), 256, 0, stream>>>(
        ctx, Woutt, 4096, 1024, 1024, bout,
        out, nullptr, nullptr, nullptr, nullptr, nullptr);
}